// Round 13
// baseline (131.352 us; speedup 1.0000x reference)
//
#include <hip/hip_runtime.h>
#include <math.h>

// Problem constants (from setup_inputs)
constexpr int Lc   = 4096;
constexpr int Bc   = 2;
constexpr int KNB  = 30;    // TOP_K
constexpr int NF   = 167;   // 16 pos + 144 rbf + 7 orient
constexpr int NC   = 128;   // output channels
constexpr int KP   = 200;   // padded K stride (bf16 elems) -> 400B row stride
constexpr int NKT  = 6;     // K-tiles of 32 (192 >= 167)
constexpr int CAP  = 512;   // fallback candidate capacity

typedef __attribute__((ext_vector_type(8))) short bf16x8;
typedef __attribute__((ext_vector_type(4))) float f32x4;

struct V3 { float x, y, z; };

__device__ __forceinline__ float sgnf(float v) {
    return (v > 0.f) ? 1.f : ((v < 0.f) ? -1.f : 0.f);
}
__device__ __forceinline__ unsigned long long umin64(unsigned long long a, unsigned long long b) {
    return a < b ? a : b;
}
__device__ __forceinline__ void splitbf(float v, unsigned short& h, unsigned short& l) {
    unsigned u = __float_as_uint(v);
    h = (unsigned short)(u >> 16);
    float fh = __uint_as_float((unsigned)h << 16);
    l = (unsigned short)(__float_as_uint(v - fh) >> 16);
}
// packed f32x2 -> bf16x2 (RTNE), single instruction; lo = a, hi = b
__device__ __forceinline__ unsigned cvtpk(float a, float b) {
    unsigned r;
    asm("v_cvt_pk_bf16_f32 %0, %1, %2" : "=v"(r) : "v"(a), "v"(b));
    return r;
}

__device__ __forceinline__ V3 unit_seg(float dx, float dy, float dz) {
    float n = sqrtf(dx * dx + dy * dy + dz * dz);
    float m = (n > 3.6f && n < 4.0f) ? 1.f : 0.f;
    float nn = fmaxf(m * n, 1e-12f);
    V3 r; r.x = dx * m / nn; r.y = dy * m / nn; r.z = dz * m / nn;
    return r;
}

// ---------------------------------------------------------------------------
// Kernel 1 (merged): blocks [0,rows) = topk (float4-vectorized loads);
// blocks [rows,rows+32) = orient; [rows+32,rows+44) = W pack.
// topk does not consume prep outputs; edge launches after -> safe ordering.
// ---------------------------------------------------------------------------
__global__ __launch_bounds__(256) void topk_prep_kernel(
    const float* __restrict__ Ca, const float* __restrict__ mask,
    float* __restrict__ EidxF, int* __restrict__ EidxI,
    float* __restrict__ O, const float* __restrict__ W,
    unsigned short* __restrict__ Wh, unsigned short* __restrict__ Wl,
    int rows) {
    const int t = threadIdx.x;

    if (blockIdx.x >= rows) {
        int pb = blockIdx.x - rows;
        if (pb < 32) {
            // --- orient ---
            int idx = pb * 256 + t;
            if (idx >= Bc * Lc) return;
            int b = idx >> 12, l = idx & (Lc - 1);
            float* o = O + (size_t)idx * 9;
            if (l < 1 || l >= Lc - 2) {
#pragma unroll
                for (int q = 0; q < 9; ++q) o[q] = 0.f;
                return;
            }
            const float* C = Ca + ((size_t)b * Lc + (l - 1)) * 3;
            V3 u2 = unit_seg(C[3] - C[0], C[4] - C[1], C[5] - C[2]);
            V3 u1 = unit_seg(C[6] - C[3], C[7] - C[4], C[8] - C[5]);
            float nx = u2.y * u1.z - u2.z * u1.y;
            float ny = u2.z * u1.x - u2.x * u1.z;
            float nz = u2.x * u1.y - u2.y * u1.x;
            float nn = fmaxf(sqrtf(nx * nx + ny * ny + nz * nz), 1e-12f);
            nx /= nn; ny /= nn; nz /= nn;
            float ox = u2.x - u1.x, oy = u2.y - u1.y, oz = u2.z - u1.z;
            float on = fmaxf(sqrtf(ox * ox + oy * oy + oz * oz), 1e-12f);
            ox /= on; oy /= on; oz /= on;
            o[0] = ox; o[1] = oy; o[2] = oz;
            o[3] = nx; o[4] = ny; o[5] = nz;
            o[6] = oy * nz - oz * ny;
            o[7] = oz * nx - ox * nz;
            o[8] = ox * ny - oy * nx;
        } else {
            // --- W pack ---
            int tt = (pb - 32) * 256 + t;
            if (tt >= NKT * 8 * 64) return;
            int lane = tt & 63, nt = (tt >> 6) & 7, kt = tt >> 9;
            int n = nt * 16 + (lane & 15);
            int kbase = kt * 32 + (lane >> 4) * 8;
            __align__(16) unsigned short h[8], l[8];
#pragma unroll
            for (int j = 0; j < 8; ++j) {
                int k = kbase + j;
                float v = (k < NF) ? W[(size_t)k * NC + n] : 0.f;
                splitbf(v, h[j], l[j]);
            }
            size_t o = (size_t)tt * 8;
            *(bf16x8*)(Wh + o) = *(const bf16x8*)h;
            *(bf16x8*)(Wl + o) = *(const bf16x8*)l;
        }
        return;
    }

    // ===================== topk =====================
    const int row = blockIdx.x;                 // b*L + i
    const int b = row >> 12, i = row & (Lc - 1);
    const float* CaB = Ca + (size_t)b * Lc * 3;
    const float* mB  = mask + (size_t)b * Lc;
    const float xi = CaB[i * 3 + 0], yi = CaB[i * 3 + 1], zi = CaB[i * 3 + 2];
    const float mi = mB[i];

    __shared__ unsigned long long cand[CAP];         // 4 KB
    __shared__ float redf[4];
    __shared__ int redi[2][4];
    __shared__ int candN;

    const int lane = t & 63, wid = t >> 6;
    if (t == 0) candN = 0;

    // 16 contiguous j per thread, float4-vectorized loads
    const int j0 = t * 16;
    const float4* Ca4 = (const float4*)(CaB + (size_t)j0 * 3);   // t*192 B aligned
    const float4* M4  = (const float4*)(mB + j0);                // t*64 B aligned

    float ss[16], m2a[16];
    float lmax = -1e30f;
#pragma unroll
    for (int u = 0; u < 4; ++u) {
        float4 c0 = Ca4[u * 3 + 0];
        float4 c1 = Ca4[u * 3 + 1];
        float4 c2 = Ca4[u * 3 + 2];
        float4 mm = M4[u];
        float px[4] = {c0.x, c0.w, c1.z, c2.y};
        float py[4] = {c0.y, c1.x, c1.w, c2.z};
        float pz[4] = {c0.z, c1.y, c2.x, c2.w};
        float pm[4] = {mm.x, mm.y, mm.z, mm.w};
#pragma unroll
        for (int q = 0; q < 4; ++q) {
            float dx = px[q] - xi, dy = py[q] - yi, dz = pz[q] - zi;
            float s = dx * dx + dy * dy + dz * dz;
            float m2 = mi * pm[q];
            float v = m2 * s;
            ss[u * 4 + q] = v; m2a[u * 4 + q] = m2;
            lmax = fmaxf(lmax, v);
        }
    }
    for (int off = 32; off; off >>= 1) lmax = fmaxf(lmax, __shfl_xor(lmax, off));
    if (lane == 0) redf[wid] = lmax;
    __syncthreads();
    const float ssmax = fmaxf(fmaxf(redf[0], redf[1]), fmaxf(redf[2], redf[3]));

#pragma unroll
    for (int k = 0; k < 16; ++k) ss[k] = ss[k] + (1.f - m2a[k]) * ssmax;

    float T = ssmax * 0.037772f;   // (30/4096)^(2/3)
    int c = 0;
    for (int iter = 0; iter < 32; ++iter) {
        int lc = 0;
#pragma unroll
        for (int k = 0; k < 16; ++k) lc += (ss[k] <= T) ? 1 : 0;
        for (int off = 32; off; off >>= 1) lc += __shfl_xor(lc, off);
        if (lane == 0) redi[iter & 1][wid] = lc;
        __syncthreads();
        c = redi[iter & 1][0] + redi[iter & 1][1] + redi[iter & 1][2] + redi[iter & 1][3];
        if (c >= KNB && c <= 64) break;
        if (iter >= 12 && c >= KNB && c <= CAP) break;
        if (c < KNB) {
            if (c == 0) T *= 2.89f;
            else {
                float f = cbrtf((float)(KNB + 15) / (float)c);
                T *= fminf(2.89f, 1.1025f * f * f);
            }
        } else {
            float f = cbrtf(45.f / (float)c);
            T *= fmaxf(0.3025f, 1.1025f * f * f);
        }
    }

#pragma unroll
    for (int k = 0; k < 16; ++k) {
        if (ss[k] <= T) {
            int idx = atomicAdd(&candN, 1);
            if (idx < CAP)
                cand[idx] = ((unsigned long long)__float_as_uint(ss[k]) << 32) |
                            (unsigned)(j0 + k);
        }
    }
    __syncthreads();

    if (wid == 0) {
        int C = candN; if (C > CAP) C = CAP;
        if (C <= 64) {
            unsigned long long key = (lane < C) ? cand[lane] : ~0ULL;
#pragma unroll
            for (int size = 2; size <= 64; size <<= 1) {
#pragma unroll
                for (int stride = size >> 1; stride; stride >>= 1) {
                    unsigned long long other = __shfl_xor(key, stride);
                    bool dirUp = ((lane & size) == 0);
                    bool takeMin = ((lane & stride) == 0) ? dirUp : !dirUp;
                    bool less = other < key;
                    unsigned long long mn = less ? other : key;
                    unsigned long long mx = less ? key : other;
                    key = takeMin ? mn : mx;
                }
            }
            if (lane < KNB) {
                int jw = (int)(key & 0xFFFFFFFFULL);
                EidxF[(size_t)row * KNB + lane] = (float)jw;
                EidxI[(size_t)row * KNB + lane] = jw;
            }
        } else {
            unsigned long long r[CAP / 64];
#pragma unroll
            for (int q = 0; q < CAP / 64; ++q) {
                int idx = lane + q * 64;
                r[q] = (idx < C) ? cand[idx] : ~0ULL;
            }
            for (int p = 0; p < KNB; ++p) {
                unsigned long long mn = r[0];
#pragma unroll
                for (int q = 1; q < CAP / 64; ++q) mn = umin64(mn, r[q]);
                for (int off = 32; off; off >>= 1) mn = umin64(mn, __shfl_xor(mn, off));
                if (lane == 0) {
                    int jw = (int)(mn & 0xFFFFFFFFULL);
                    EidxF[(size_t)row * KNB + p] = (float)jw;
                    EidxI[(size_t)row * KNB + p] = jw;
                }
#pragma unroll
                for (int q = 0; q < CAP / 64; ++q) if (r[q] == mn) r[q] = ~0ULL;
            }
        }
    }
}

// ---------------------------------------------------------------------------
// Kernel 2 (v6): features (uniform-branch layout, cvt_pk packing) + MFMA +
// in-register LayerNorm (unchanged from R12).
// ---------------------------------------------------------------------------
__global__ __launch_bounds__(256) void edge_kernel(
    const float* __restrict__ Ca, const int* __restrict__ ridx,
    const int* __restrict__ clab, const float* __restrict__ pos_W,
    const float* __restrict__ pos_b,
    const unsigned short* __restrict__ Wh, const unsigned short* __restrict__ Wl,
    const float* __restrict__ ln_g, const float* __restrict__ ln_b,
    const int* __restrict__ EidxI, const float* __restrict__ Omat,
    float* __restrict__ outE) {
    const int row = blockIdx.x;                 // b*L + i
    const int b = row >> 12, i = row & (Lc - 1);
    const int tid = threadIdx.x, lane = tid & 63, w = tid >> 6;

    __shared__ __align__(16) unsigned short Fh[32][KP];   // 12.5 KB
    __shared__ float Ssum[32][4];
    __shared__ float Ssq[32][4];
    __shared__ float2 Mstat[32];
    __shared__ int Ej[32];

    const float* CaB = Ca + (size_t)b * Lc * 3;

    // --- targeted zero-fill: padding cols 167..199 all rows; rows 30,31 ---
    for (int q = tid; q < 32 * 33; q += 256) {
        int r = q / 33, c = 167 + q % 33;
        Fh[r][c] = 0;
    }
    for (int q = tid; q < 2 * 167; q += 256) {
        int r = 30 + q / 167, c = q % 167;
        Fh[r][c] = 0;
    }
    if (tid < KNB) Ej[tid] = EidxI[(size_t)row * KNB + tid];
    __syncthreads();

    auto putF2 = [&](int e, int k, float va, float vb) {   // k even
        *(unsigned*)&Fh[e][k] = cvtpk(va, vb);
    };
    auto loadC = [&](int n) {
        V3 r;
        if (n >= 0 && n < Lc) { r.x = CaB[n*3]; r.y = CaB[n*3+1]; r.z = CaB[n*3+2]; }
        else { r.x = 0.f; r.y = 0.f; r.z = 0.f; }
        return r;
    };

    // RBF body: task r in [0,270): e = r%30, g = r/30+1; shifts packed in bits.
    auto rbf_task = [&](int r) {
        int e = r % 30, g = r / 30 + 1;
        int j = Ej[e];
        int pa = (int)((0xA5084u >> (2 * g)) & 3u);
        int pb = (int)((0x48984u >> (2 * g)) & 3u);
        V3 A = loadC(i - 1 + pa);
        V3 B = loadC(j - 1 + pb);
        float dx = A.x - B.x, dy = A.y - B.y, dz = A.z - B.z;
        float D8 = sqrtf(dx * dx + dy * dy + dz * dz + 1e-6f) * (1.f / 1.25f);
        int k0 = 16 * g;
#pragma unroll
        for (int m = 0; m < 16; m += 2) {
            float z0 = D8 - (2.f + (20.f / 15.f) * (float)m) * (1.f / 1.25f);
            float z1 = D8 - (2.f + (20.f / 15.f) * (float)(m + 1)) * (1.f / 1.25f);
            putF2(e, k0 + m, __expf(-z0 * z0), __expf(-z1 * z1));
        }
    };

    // Round 1: fully uniform — every thread one RBF task.
    rbf_task(tid);

    // Round 2: one branch body per wave.
    if (w == 0) {
        if (lane < 14) rbf_task(256 + lane);
    } else if (w == 1) {
        if (lane < KNB) {
            int e = lane, j = Ej[e];
            int off = ridx[(size_t)b * Lc + i] - ridx[(size_t)b * Lc + j];
            int ec = (clab[(size_t)b * Lc + i] == clab[(size_t)b * Lc + j]) ? 1 : 0;
            int d = ec ? min(max(off + 32, 0), 64) : 65;
#pragma unroll
            for (int cc = 0; cc < 16; cc += 2)
                putF2(e, cc, pos_W[d * 16 + cc] + pos_b[cc],
                             pos_W[d * 16 + cc + 1] + pos_b[cc + 1]);
        }
    } else if (w == 2) {
        if (lane < KNB) {
            int e = lane, j = Ej[e];
            const float* Om = Omat + (size_t)row * 9;
            const float* On = Omat + ((size_t)b * Lc + j) * 9;
            V3 Ai = loadC(i), Bj = loadC(j);
            float dvx = Bj.x - Ai.x, dvy = Bj.y - Ai.y, dvz = Bj.z - Ai.z;
            float u0 = Om[0] * dvx + Om[1] * dvy + Om[2] * dvz;
            float u1 = Om[3] * dvx + Om[4] * dvy + Om[5] * dvz;
            float u2 = Om[6] * dvx + Om[7] * dvy + Om[8] * dvz;
            float un = fmaxf(sqrtf(u0 * u0 + u1 * u1 + u2 * u2), 1e-12f);
            float R[3][3];
#pragma unroll
            for (int a = 0; a < 3; ++a)
#pragma unroll
                for (int m = 0; m < 3; ++m)
                    R[a][m] = Om[0 * 3 + a] * On[0 * 3 + m] +
                              Om[1 * 3 + a] * On[1 * 3 + m] +
                              Om[2 * 3 + a] * On[2 * 3 + m];
            float Rxx = R[0][0], Ryy = R[1][1], Rzz = R[2][2];
            float m0 = 0.5f * sqrtf(fabsf(1.f + Rxx - Ryy - Rzz));
            float m1 = 0.5f * sqrtf(fabsf(1.f - Rxx + Ryy - Rzz));
            float m2 = 0.5f * sqrtf(fabsf(1.f - Rxx - Ryy + Rzz));
            float qx = sgnf(R[2][1] - R[1][2]) * m0;
            float qy = sgnf(R[0][2] - R[2][0]) * m1;
            float qz = sgnf(R[1][0] - R[0][1]) * m2;
            float qw = sqrtf(fmaxf(0.f, 1.f + Rxx + Ryy + Rzz)) * 0.5f;
            float qn = fmaxf(sqrtf(qx * qx + qy * qy + qz * qz + qw * qw), 1e-12f);
            putF2(e, 160, u0 / un, u1 / un);
            putF2(e, 162, u2 / un, qx / qn);
            putF2(e, 164, qy / qn, qz / qn);
            putF2(e, 166, qw / qn, 0.f);      // col 167 is zero padding
        }
    }
    __syncthreads();

    // --- MFMA phase: wave w owns N columns [w*32, w*32+32) ---
    const int arow = lane & 15, agrp = lane >> 4;
    const int ng0 = w * 2;
    f32x4 acc[2][2];
#pragma unroll
    for (int m = 0; m < 2; ++m)
#pragma unroll
        for (int n = 0; n < 2; ++n) acc[m][n] = (f32x4){0.f, 0.f, 0.f, 0.f};

    const bf16x8* WhF = (const bf16x8*)Wh;
    const bf16x8* WlF = (const bf16x8*)Wl;

#pragma unroll
    for (int kt = 0; kt < NKT; ++kt) {
        const int kof = kt * 32 + agrp * 8;
        bf16x8 a0 = *(const bf16x8*)&Fh[arow][kof];
        bf16x8 a1 = *(const bf16x8*)&Fh[16 + arow][kof];
        bf16x8 b0h = WhF[(kt * 8 + ng0) * 64 + lane];
        bf16x8 b1h = WhF[(kt * 8 + ng0 + 1) * 64 + lane];
        bf16x8 b0l = WlF[(kt * 8 + ng0) * 64 + lane];
        bf16x8 b1l = WlF[(kt * 8 + ng0 + 1) * 64 + lane];

        acc[0][0] = __builtin_amdgcn_mfma_f32_16x16x32_bf16(a0, b0h, acc[0][0], 0, 0, 0);
        acc[0][0] = __builtin_amdgcn_mfma_f32_16x16x32_bf16(a0, b0l, acc[0][0], 0, 0, 0);
        acc[0][1] = __builtin_amdgcn_mfma_f32_16x16x32_bf16(a0, b1h, acc[0][1], 0, 0, 0);
        acc[0][1] = __builtin_amdgcn_mfma_f32_16x16x32_bf16(a0, b1l, acc[0][1], 0, 0, 0);
        acc[1][0] = __builtin_amdgcn_mfma_f32_16x16x32_bf16(a1, b0h, acc[1][0], 0, 0, 0);
        acc[1][0] = __builtin_amdgcn_mfma_f32_16x16x32_bf16(a1, b0l, acc[1][0], 0, 0, 0);
        acc[1][1] = __builtin_amdgcn_mfma_f32_16x16x32_bf16(a1, b1h, acc[1][1], 0, 0, 0);
        acc[1][1] = __builtin_amdgcn_mfma_f32_16x16x32_bf16(a1, b1l, acc[1][1], 0, 0, 0);
    }

    // --- LN stats from accumulators ---
    float ps[2][4], pq[2][4];
#pragma unroll
    for (int m = 0; m < 2; ++m)
#pragma unroll
        for (int r = 0; r < 4; ++r) {
            float v0 = acc[m][0][r], v1 = acc[m][1][r];
            ps[m][r] = v0 + v1;
            pq[m][r] = v0 * v0 + v1 * v1;
        }
#pragma unroll
    for (int off = 1; off < 16; off <<= 1) {
#pragma unroll
        for (int m = 0; m < 2; ++m)
#pragma unroll
            for (int r = 0; r < 4; ++r) {
                ps[m][r] += __shfl_xor(ps[m][r], off);
                pq[m][r] += __shfl_xor(pq[m][r], off);
            }
    }
    if (arow == 0) {
#pragma unroll
        for (int m = 0; m < 2; ++m)
#pragma unroll
            for (int r = 0; r < 4; ++r) {
                int me = m * 16 + agrp * 4 + r;
                Ssum[me][w] = ps[m][r];
                Ssq[me][w] = pq[m][r];
            }
    }
    __syncthreads();
    if (tid < 32) {
        float s = Ssum[tid][0] + Ssum[tid][1] + Ssum[tid][2] + Ssum[tid][3];
        float q = Ssq[tid][0] + Ssq[tid][1] + Ssq[tid][2] + Ssq[tid][3];
        float mean = s * (1.f / 128.f);
        float var = q * (1.f / 128.f) - mean * mean;
        Mstat[tid] = make_float2(mean, 1.f / sqrtf(var + 1e-5f));
    }
    __syncthreads();

    float gg[2], bb[2];
#pragma unroll
    for (int n = 0; n < 2; ++n) {
        int ce = (ng0 + n) * 16 + arow;
        gg[n] = ln_g[ce];
        bb[n] = ln_b[ce];
    }
#pragma unroll
    for (int m = 0; m < 2; ++m)
#pragma unroll
        for (int r = 0; r < 4; ++r) {
            int me = m * 16 + agrp * 4 + r;
            if (me >= KNB) continue;
            float2 st = Mstat[me];
            size_t base = ((size_t)row * KNB + me) * NC;
#pragma unroll
            for (int n = 0; n < 2; ++n) {
                int ce = (ng0 + n) * 16 + arow;
                outE[base + ce] = (acc[m][n][r] - st.x) * st.y * gg[n] + bb[n];
            }
        }
}

// ---------------------------------------------------------------------------
extern "C" void kernel_launch(void* const* d_in, const int* in_sizes, int n_in,
                              void* d_out, int out_size, void* d_ws, size_t ws_size,
                              hipStream_t stream) {
    const float* Ca     = (const float*)d_in[0];
    const float* mask   = (const float*)d_in[1];
    const int*   ridx   = (const int*)d_in[2];
    const int*   clab   = (const int*)d_in[3];
    const float* pos_W  = (const float*)d_in[4];
    const float* pos_b  = (const float*)d_in[5];
    const float* edge_W = (const float*)d_in[6];
    const float* ln_g   = (const float*)d_in[7];
    const float* ln_b   = (const float*)d_in[8];

    float* outE  = (float*)d_out;
    float* EidxF = outE + (size_t)Bc * Lc * KNB * NC;   // output 1 (as float values)

    float* Omat  = (float*)d_ws;                           // B*L*9 f32
    int*   EidxI = (int*)(Omat + (size_t)Bc * Lc * 9);     // B*L*30 i32
    unsigned short* Wh = (unsigned short*)(EidxI + (size_t)Bc * Lc * KNB);
    unsigned short* Wl = Wh + (size_t)NKT * 8 * 64 * 8;    // 24576 each

    const int rows = Bc * Lc;
    topk_prep_kernel<<<rows + 44, 256, 0, stream>>>(Ca, mask, EidxF, EidxI,
                                                    Omat, edge_W, Wh, Wl, rows);
    edge_kernel<<<rows, 256, 0, stream>>>(Ca, ridx, clab, pos_W, pos_b, Wh, Wl,
                                          ln_g, ln_b, EidxI, Omat, outE);
}

// Round 14
// 115.866 us; speedup vs baseline: 1.1337x; 1.1337x over previous
//
#include <hip/hip_runtime.h>
#include <math.h>

// Problem constants (from setup_inputs)
constexpr int Lc   = 4096;
constexpr int Bc   = 2;
constexpr int KNB  = 30;    // TOP_K
constexpr int NF   = 167;   // 16 pos + 144 rbf + 7 orient
constexpr int NC   = 128;   // output channels
constexpr int KP   = 200;   // padded K stride (bf16 elems) -> 400B row stride
constexpr int NKT  = 6;     // K-tiles of 32 (192 >= 167)
constexpr int CAP  = 512;   // fallback candidate capacity

typedef __attribute__((ext_vector_type(8))) short bf16x8;
typedef __attribute__((ext_vector_type(4))) float f32x4;

struct V3 { float x, y, z; };

__device__ __forceinline__ float sgnf(float v) {
    return (v > 0.f) ? 1.f : ((v < 0.f) ? -1.f : 0.f);
}
__device__ __forceinline__ unsigned long long umin64(unsigned long long a, unsigned long long b) {
    return a < b ? a : b;
}
__device__ __forceinline__ void splitbf(float v, unsigned short& h, unsigned short& l) {
    unsigned u = __float_as_uint(v);
    h = (unsigned short)(u >> 16);
    float fh = __uint_as_float((unsigned)h << 16);
    l = (unsigned short)(__float_as_uint(v - fh) >> 16);
}
// packed f32x2 -> bf16x2 (RTNE), single instruction; lo = a, hi = b
__device__ __forceinline__ unsigned cvtpk(float a, float b) {
    unsigned r;
    asm("v_cvt_pk_bf16_f32 %0, %1, %2" : "=v"(r) : "v"(a), "v"(b));
    return r;
}

__device__ __forceinline__ V3 unit_seg(float dx, float dy, float dz) {
    float n = sqrtf(dx * dx + dy * dy + dz * dz);
    float m = (n > 3.6f && n < 4.0f) ? 1.f : 0.f;
    float nn = fmaxf(m * n, 1e-12f);
    V3 r; r.x = dx * m / nn; r.y = dy * m / nn; r.z = dz * m / nn;
    return r;
}

// ---------------------------------------------------------------------------
// Kernel 1 (merged): blocks [0,rows) = topk (R12 strided coalesced loads +
// 4-probe threshold bracketing); [rows,rows+32) = orient; rest = W pack.
// ---------------------------------------------------------------------------
__global__ __launch_bounds__(256) void topk_prep_kernel(
    const float* __restrict__ Ca, const float* __restrict__ mask,
    float* __restrict__ EidxF, int* __restrict__ EidxI,
    float* __restrict__ O, const float* __restrict__ W,
    unsigned short* __restrict__ Wh, unsigned short* __restrict__ Wl,
    int rows) {
    const int t = threadIdx.x;

    if (blockIdx.x >= rows) {
        int pb = blockIdx.x - rows;
        if (pb < 32) {
            // --- orient ---
            int idx = pb * 256 + t;
            if (idx >= Bc * Lc) return;
            int b = idx >> 12, l = idx & (Lc - 1);
            float* o = O + (size_t)idx * 9;
            if (l < 1 || l >= Lc - 2) {
#pragma unroll
                for (int q = 0; q < 9; ++q) o[q] = 0.f;
                return;
            }
            const float* C = Ca + ((size_t)b * Lc + (l - 1)) * 3;
            V3 u2 = unit_seg(C[3] - C[0], C[4] - C[1], C[5] - C[2]);
            V3 u1 = unit_seg(C[6] - C[3], C[7] - C[4], C[8] - C[5]);
            float nx = u2.y * u1.z - u2.z * u1.y;
            float ny = u2.z * u1.x - u2.x * u1.z;
            float nz = u2.x * u1.y - u2.y * u1.x;
            float nn = fmaxf(sqrtf(nx * nx + ny * ny + nz * nz), 1e-12f);
            nx /= nn; ny /= nn; nz /= nn;
            float ox = u2.x - u1.x, oy = u2.y - u1.y, oz = u2.z - u1.z;
            float on = fmaxf(sqrtf(ox * ox + oy * oy + oz * oz), 1e-12f);
            ox /= on; oy /= on; oz /= on;
            o[0] = ox; o[1] = oy; o[2] = oz;
            o[3] = nx; o[4] = ny; o[5] = nz;
            o[6] = oy * nz - oz * ny;
            o[7] = oz * nx - ox * nz;
            o[8] = ox * ny - oy * nx;
        } else {
            // --- W pack ---
            int tt = (pb - 32) * 256 + t;
            if (tt >= NKT * 8 * 64) return;
            int lane = tt & 63, nt = (tt >> 6) & 7, kt = tt >> 9;
            int n = nt * 16 + (lane & 15);
            int kbase = kt * 32 + (lane >> 4) * 8;
            __align__(16) unsigned short h[8], l[8];
#pragma unroll
            for (int j = 0; j < 8; ++j) {
                int k = kbase + j;
                float v = (k < NF) ? W[(size_t)k * NC + n] : 0.f;
                splitbf(v, h[j], l[j]);
            }
            size_t o = (size_t)tt * 8;
            *(bf16x8*)(Wh + o) = *(const bf16x8*)h;
            *(bf16x8*)(Wl + o) = *(const bf16x8*)l;
        }
        return;
    }

    // ===================== topk =====================
    const int row = blockIdx.x;                 // b*L + i
    const int b = row >> 12, i = row & (Lc - 1);
    const float* CaB = Ca + (size_t)b * Lc * 3;
    const float* mB  = mask + (size_t)b * Lc;
    const float xi = CaB[i * 3 + 0], yi = CaB[i * 3 + 1], zi = CaB[i * 3 + 2];
    const float mi = mB[i];

    __shared__ unsigned long long cand[CAP];         // 4 KB
    __shared__ float redf[4];
    __shared__ int redi[2][4];
    __shared__ int redi4[4][4];                      // [wid][probe]
    __shared__ int candN;

    const int lane = t & 63, wid = t >> 6;
    if (t == 0) candN = 0;

    // squared distances in registers, strided (lane stride 12 B = coalesced)
    float ss[16], m2a[16];
    float lmax = -1e30f;
#pragma unroll
    for (int k = 0; k < 16; ++k) {
        int j = t + k * 256;
        float dx = CaB[j * 3 + 0] - xi;
        float dy = CaB[j * 3 + 1] - yi;
        float dz = CaB[j * 3 + 2] - zi;
        float s = dx * dx + dy * dy + dz * dz;
        float m2 = mi * mB[j];
        float v = m2 * s;
        ss[k] = v; m2a[k] = m2;
        lmax = fmaxf(lmax, v);
    }
    for (int off = 32; off; off >>= 1) lmax = fmaxf(lmax, __shfl_xor(lmax, off));
    if (lane == 0) redf[wid] = lmax;
    __syncthreads();
    const float ssmax = fmaxf(fmaxf(redf[0], redf[1]), fmaxf(redf[2], redf[3]));

#pragma unroll
    for (int k = 0; k < 16; ++k) ss[k] = ss[k] + (1.f - m2a[k]) * ssmax;

    // --- round 0: 4-probe bracket (one barrier) ---
    const float Tb = ssmax * 0.037772f;   // (30/4096)^(2/3)
    float T;
    int c;
    {
        const float t0 = Tb, t1 = Tb * 3.f, t2 = Tb * 9.f, t3 = Tb * 27.f;
        int l0 = 0, l1 = 0, l2 = 0, l3 = 0;
#pragma unroll
        for (int k = 0; k < 16; ++k) {
            float v = ss[k];
            l0 += (v <= t0) ? 1 : 0;
            l1 += (v <= t1) ? 1 : 0;
            l2 += (v <= t2) ? 1 : 0;
            l3 += (v <= t3) ? 1 : 0;
        }
        for (int off = 32; off; off >>= 1) {
            l0 += __shfl_xor(l0, off); l1 += __shfl_xor(l1, off);
            l2 += __shfl_xor(l2, off); l3 += __shfl_xor(l3, off);
        }
        if (lane == 0) {
            redi4[wid][0] = l0; redi4[wid][1] = l1;
            redi4[wid][2] = l2; redi4[wid][3] = l3;
        }
        __syncthreads();
        int c0 = redi4[0][0] + redi4[1][0] + redi4[2][0] + redi4[3][0];
        int c1 = redi4[0][1] + redi4[1][1] + redi4[2][1] + redi4[3][1];
        int c2 = redi4[0][2] + redi4[1][2] + redi4[2][2] + redi4[3][2];
        int c3 = redi4[0][3] + redi4[1][3] + redi4[2][3] + redi4[3][3];
        // smallest probe with c >= KNB (else the largest as expansion start)
        if (c0 >= KNB)      { T = t0; c = c0; }
        else if (c1 >= KNB) { T = t1; c = c1; }
        else if (c2 >= KNB) { T = t2; c = c2; }
        else                { T = t3; c = c3; }
    }

    // --- sequential refine (usually 0-2 iterations) ---
    for (int iter = 1; iter < 32; ++iter) {
        if (c >= KNB && c <= 64) break;
        if (iter >= 12 && c >= KNB && c <= CAP) break;
        if (c < KNB) {
            if (c == 0) T *= 2.89f;
            else {
                float f = cbrtf((float)(KNB + 15) / (float)c);
                T *= fminf(2.89f, 1.1025f * f * f);
            }
        } else {
            float f = cbrtf(45.f / (float)c);
            T *= fmaxf(0.3025f, 1.1025f * f * f);
        }
        int lc = 0;
#pragma unroll
        for (int k = 0; k < 16; ++k) lc += (ss[k] <= T) ? 1 : 0;
        for (int off = 32; off; off >>= 1) lc += __shfl_xor(lc, off);
        if (lane == 0) redi[iter & 1][wid] = lc;
        __syncthreads();
        c = redi[iter & 1][0] + redi[iter & 1][1] + redi[iter & 1][2] + redi[iter & 1][3];
    }

    // collect candidates (<= T)
#pragma unroll
    for (int k = 0; k < 16; ++k) {
        if (ss[k] <= T) {
            int idx = atomicAdd(&candN, 1);
            if (idx < CAP)
                cand[idx] = ((unsigned long long)__float_as_uint(ss[k]) << 32) |
                            (unsigned)(t + k * 256);
        }
    }
    __syncthreads();

    if (wid == 0) {
        int C = candN; if (C > CAP) C = CAP;
        if (C <= 64) {
            unsigned long long key = (lane < C) ? cand[lane] : ~0ULL;
#pragma unroll
            for (int size = 2; size <= 64; size <<= 1) {
#pragma unroll
                for (int stride = size >> 1; stride; stride >>= 1) {
                    unsigned long long other = __shfl_xor(key, stride);
                    bool dirUp = ((lane & size) == 0);
                    bool takeMin = ((lane & stride) == 0) ? dirUp : !dirUp;
                    bool less = other < key;
                    unsigned long long mn = less ? other : key;
                    unsigned long long mx = less ? key : other;
                    key = takeMin ? mn : mx;
                }
            }
            if (lane < KNB) {
                int jw = (int)(key & 0xFFFFFFFFULL);
                EidxF[(size_t)row * KNB + lane] = (float)jw;
                EidxI[(size_t)row * KNB + lane] = jw;
            }
        } else {
            unsigned long long r[CAP / 64];
#pragma unroll
            for (int q = 0; q < CAP / 64; ++q) {
                int idx = lane + q * 64;
                r[q] = (idx < C) ? cand[idx] : ~0ULL;
            }
            for (int p = 0; p < KNB; ++p) {
                unsigned long long mn = r[0];
#pragma unroll
                for (int q = 1; q < CAP / 64; ++q) mn = umin64(mn, r[q]);
                for (int off = 32; off; off >>= 1) mn = umin64(mn, __shfl_xor(mn, off));
                if (lane == 0) {
                    int jw = (int)(mn & 0xFFFFFFFFULL);
                    EidxF[(size_t)row * KNB + p] = (float)jw;
                    EidxI[(size_t)row * KNB + p] = jw;
                }
#pragma unroll
                for (int q = 0; q < CAP / 64; ++q) if (r[q] == mn) r[q] = ~0ULL;
            }
        }
    }
}

// ---------------------------------------------------------------------------
// Kernel 2 (v6): features (uniform-branch layout, cvt_pk packing) + MFMA +
// in-register LayerNorm (unchanged from R12).
// ---------------------------------------------------------------------------
__global__ __launch_bounds__(256) void edge_kernel(
    const float* __restrict__ Ca, const int* __restrict__ ridx,
    const int* __restrict__ clab, const float* __restrict__ pos_W,
    const float* __restrict__ pos_b,
    const unsigned short* __restrict__ Wh, const unsigned short* __restrict__ Wl,
    const float* __restrict__ ln_g, const float* __restrict__ ln_b,
    const int* __restrict__ EidxI, const float* __restrict__ Omat,
    float* __restrict__ outE) {
    const int row = blockIdx.x;                 // b*L + i
    const int b = row >> 12, i = row & (Lc - 1);
    const int tid = threadIdx.x, lane = tid & 63, w = tid >> 6;

    __shared__ __align__(16) unsigned short Fh[32][KP];   // 12.5 KB
    __shared__ float Ssum[32][4];
    __shared__ float Ssq[32][4];
    __shared__ float2 Mstat[32];
    __shared__ int Ej[32];

    const float* CaB = Ca + (size_t)b * Lc * 3;

    // --- targeted zero-fill: padding cols 167..199 all rows; rows 30,31 ---
    for (int q = tid; q < 32 * 33; q += 256) {
        int r = q / 33, c = 167 + q % 33;
        Fh[r][c] = 0;
    }
    for (int q = tid; q < 2 * 167; q += 256) {
        int r = 30 + q / 167, c = q % 167;
        Fh[r][c] = 0;
    }
    if (tid < KNB) Ej[tid] = EidxI[(size_t)row * KNB + tid];
    __syncthreads();

    auto putF2 = [&](int e, int k, float va, float vb) {   // k even
        *(unsigned*)&Fh[e][k] = cvtpk(va, vb);
    };
    auto loadC = [&](int n) {
        V3 r;
        if (n >= 0 && n < Lc) { r.x = CaB[n*3]; r.y = CaB[n*3+1]; r.z = CaB[n*3+2]; }
        else { r.x = 0.f; r.y = 0.f; r.z = 0.f; }
        return r;
    };

    // RBF body: task r in [0,270): e = r%30, g = r/30+1; shifts packed in bits.
    auto rbf_task = [&](int r) {
        int e = r % 30, g = r / 30 + 1;
        int j = Ej[e];
        int pa = (int)((0xA5084u >> (2 * g)) & 3u);
        int pb = (int)((0x48984u >> (2 * g)) & 3u);
        V3 A = loadC(i - 1 + pa);
        V3 B = loadC(j - 1 + pb);
        float dx = A.x - B.x, dy = A.y - B.y, dz = A.z - B.z;
        float D8 = sqrtf(dx * dx + dy * dy + dz * dz + 1e-6f) * (1.f / 1.25f);
        int k0 = 16 * g;
#pragma unroll
        for (int m = 0; m < 16; m += 2) {
            float z0 = D8 - (2.f + (20.f / 15.f) * (float)m) * (1.f / 1.25f);
            float z1 = D8 - (2.f + (20.f / 15.f) * (float)(m + 1)) * (1.f / 1.25f);
            putF2(e, k0 + m, __expf(-z0 * z0), __expf(-z1 * z1));
        }
    };

    // Round 1: fully uniform — every thread one RBF task.
    rbf_task(tid);

    // Round 2: one branch body per wave.
    if (w == 0) {
        if (lane < 14) rbf_task(256 + lane);
    } else if (w == 1) {
        if (lane < KNB) {
            int e = lane, j = Ej[e];
            int off = ridx[(size_t)b * Lc + i] - ridx[(size_t)b * Lc + j];
            int ec = (clab[(size_t)b * Lc + i] == clab[(size_t)b * Lc + j]) ? 1 : 0;
            int d = ec ? min(max(off + 32, 0), 64) : 65;
#pragma unroll
            for (int cc = 0; cc < 16; cc += 2)
                putF2(e, cc, pos_W[d * 16 + cc] + pos_b[cc],
                             pos_W[d * 16 + cc + 1] + pos_b[cc + 1]);
        }
    } else if (w == 2) {
        if (lane < KNB) {
            int e = lane, j = Ej[e];
            const float* Om = Omat + (size_t)row * 9;
            const float* On = Omat + ((size_t)b * Lc + j) * 9;
            V3 Ai = loadC(i), Bj = loadC(j);
            float dvx = Bj.x - Ai.x, dvy = Bj.y - Ai.y, dvz = Bj.z - Ai.z;
            float u0 = Om[0] * dvx + Om[1] * dvy + Om[2] * dvz;
            float u1 = Om[3] * dvx + Om[4] * dvy + Om[5] * dvz;
            float u2 = Om[6] * dvx + Om[7] * dvy + Om[8] * dvz;
            float un = fmaxf(sqrtf(u0 * u0 + u1 * u1 + u2 * u2), 1e-12f);
            float R[3][3];
#pragma unroll
            for (int a = 0; a < 3; ++a)
#pragma unroll
                for (int m = 0; m < 3; ++m)
                    R[a][m] = Om[0 * 3 + a] * On[0 * 3 + m] +
                              Om[1 * 3 + a] * On[1 * 3 + m] +
                              Om[2 * 3 + a] * On[2 * 3 + m];
            float Rxx = R[0][0], Ryy = R[1][1], Rzz = R[2][2];
            float m0 = 0.5f * sqrtf(fabsf(1.f + Rxx - Ryy - Rzz));
            float m1 = 0.5f * sqrtf(fabsf(1.f - Rxx + Ryy - Rzz));
            float m2 = 0.5f * sqrtf(fabsf(1.f - Rxx - Ryy + Rzz));
            float qx = sgnf(R[2][1] - R[1][2]) * m0;
            float qy = sgnf(R[0][2] - R[2][0]) * m1;
            float qz = sgnf(R[1][0] - R[0][1]) * m2;
            float qw = sqrtf(fmaxf(0.f, 1.f + Rxx + Ryy + Rzz)) * 0.5f;
            float qn = fmaxf(sqrtf(qx * qx + qy * qy + qz * qz + qw * qw), 1e-12f);
            putF2(e, 160, u0 / un, u1 / un);
            putF2(e, 162, u2 / un, qx / qn);
            putF2(e, 164, qy / qn, qz / qn);
            putF2(e, 166, qw / qn, 0.f);      // col 167 is zero padding
        }
    }
    __syncthreads();

    // --- MFMA phase: wave w owns N columns [w*32, w*32+32) ---
    const int arow = lane & 15, agrp = lane >> 4;
    const int ng0 = w * 2;
    f32x4 acc[2][2];
#pragma unroll
    for (int m = 0; m < 2; ++m)
#pragma unroll
        for (int n = 0; n < 2; ++n) acc[m][n] = (f32x4){0.f, 0.f, 0.f, 0.f};

    const bf16x8* WhF = (const bf16x8*)Wh;
    const bf16x8* WlF = (const bf16x8*)Wl;

#pragma unroll
    for (int kt = 0; kt < NKT; ++kt) {
        const int kof = kt * 32 + agrp * 8;
        bf16x8 a0 = *(const bf16x8*)&Fh[arow][kof];
        bf16x8 a1 = *(const bf16x8*)&Fh[16 + arow][kof];
        bf16x8 b0h = WhF[(kt * 8 + ng0) * 64 + lane];
        bf16x8 b1h = WhF[(kt * 8 + ng0 + 1) * 64 + lane];
        bf16x8 b0l = WlF[(kt * 8 + ng0) * 64 + lane];
        bf16x8 b1l = WlF[(kt * 8 + ng0 + 1) * 64 + lane];

        acc[0][0] = __builtin_amdgcn_mfma_f32_16x16x32_bf16(a0, b0h, acc[0][0], 0, 0, 0);
        acc[0][0] = __builtin_amdgcn_mfma_f32_16x16x32_bf16(a0, b0l, acc[0][0], 0, 0, 0);
        acc[0][1] = __builtin_amdgcn_mfma_f32_16x16x32_bf16(a0, b1h, acc[0][1], 0, 0, 0);
        acc[0][1] = __builtin_amdgcn_mfma_f32_16x16x32_bf16(a0, b1l, acc[0][1], 0, 0, 0);
        acc[1][0] = __builtin_amdgcn_mfma_f32_16x16x32_bf16(a1, b0h, acc[1][0], 0, 0, 0);
        acc[1][0] = __builtin_amdgcn_mfma_f32_16x16x32_bf16(a1, b0l, acc[1][0], 0, 0, 0);
        acc[1][1] = __builtin_amdgcn_mfma_f32_16x16x32_bf16(a1, b1h, acc[1][1], 0, 0, 0);
        acc[1][1] = __builtin_amdgcn_mfma_f32_16x16x32_bf16(a1, b1l, acc[1][1], 0, 0, 0);
    }

    // --- LN stats from accumulators ---
    float ps[2][4], pq[2][4];
#pragma unroll
    for (int m = 0; m < 2; ++m)
#pragma unroll
        for (int r = 0; r < 4; ++r) {
            float v0 = acc[m][0][r], v1 = acc[m][1][r];
            ps[m][r] = v0 + v1;
            pq[m][r] = v0 * v0 + v1 * v1;
        }
#pragma unroll
    for (int off = 1; off < 16; off <<= 1) {
#pragma unroll
        for (int m = 0; m < 2; ++m)
#pragma unroll
            for (int r = 0; r < 4; ++r) {
                ps[m][r] += __shfl_xor(ps[m][r], off);
                pq[m][r] += __shfl_xor(pq[m][r], off);
            }
    }
    if (arow == 0) {
#pragma unroll
        for (int m = 0; m < 2; ++m)
#pragma unroll
            for (int r = 0; r < 4; ++r) {
                int me = m * 16 + agrp * 4 + r;
                Ssum[me][w] = ps[m][r];
                Ssq[me][w] = pq[m][r];
            }
    }
    __syncthreads();
    if (tid < 32) {
        float s = Ssum[tid][0] + Ssum[tid][1] + Ssum[tid][2] + Ssum[tid][3];
        float q = Ssq[tid][0] + Ssq[tid][1] + Ssq[tid][2] + Ssq[tid][3];
        float mean = s * (1.f / 128.f);
        float var = q * (1.f / 128.f) - mean * mean;
        Mstat[tid] = make_float2(mean, 1.f / sqrtf(var + 1e-5f));
    }
    __syncthreads();

    float gg[2], bb[2];
#pragma unroll
    for (int n = 0; n < 2; ++n) {
        int ce = (ng0 + n) * 16 + arow;
        gg[n] = ln_g[ce];
        bb[n] = ln_b[ce];
    }
#pragma unroll
    for (int m = 0; m < 2; ++m)
#pragma unroll
        for (int r = 0; r < 4; ++r) {
            int me = m * 16 + agrp * 4 + r;
            if (me >= KNB) continue;
            float2 st = Mstat[me];
            size_t base = ((size_t)row * KNB + me) * NC;
#pragma unroll
            for (int n = 0; n < 2; ++n) {
                int ce = (ng0 + n) * 16 + arow;
                outE[base + ce] = (acc[m][n][r] - st.x) * st.y * gg[n] + bb[n];
            }
        }
}

// ---------------------------------------------------------------------------
extern "C" void kernel_launch(void* const* d_in, const int* in_sizes, int n_in,
                              void* d_out, int out_size, void* d_ws, size_t ws_size,
                              hipStream_t stream) {
    const float* Ca     = (const float*)d_in[0];
    const float* mask   = (const float*)d_in[1];
    const int*   ridx   = (const int*)d_in[2];
    const int*   clab   = (const int*)d_in[3];
    const float* pos_W  = (const float*)d_in[4];
    const float* pos_b  = (const float*)d_in[5];
    const float* edge_W = (const float*)d_in[6];
    const float* ln_g   = (const float*)d_in[7];
    const float* ln_b   = (const float*)d_in[8];

    float* outE  = (float*)d_out;
    float* EidxF = outE + (size_t)Bc * Lc * KNB * NC;   // output 1 (as float values)

    float* Omat  = (float*)d_ws;                           // B*L*9 f32
    int*   EidxI = (int*)(Omat + (size_t)Bc * Lc * 9);     // B*L*30 i32
    unsigned short* Wh = (unsigned short*)(EidxI + (size_t)Bc * Lc * KNB);
    unsigned short* Wl = Wh + (size_t)NKT * 8 * 64 * 8;    // 24576 each

    const int rows = Bc * Lc;
    topk_prep_kernel<<<rows + 44, 256, 0, stream>>>(Ca, mask, EidxF, EidxI,
                                                    Omat, edge_W, Wh, Wl, rows);
    edge_kernel<<<rows, 256, 0, stream>>>(Ca, ridx, clab, pos_W, pos_b, Wh, Wl,
                                          ln_g, ln_b, EidxI, Omat, outE);
}